// Round 12
// baseline (271.013 us; speedup 1.0000x reference)
//
#include <hip/hip_runtime.h>

// R37 — FINAL REVERT to best-measured production kernel (R25 structure,
// 260.3us session-best). Diagnostic arc closed:
//  - NT stores (R29), 16KB runs (R31), fill-clone expander (R32), 2x-write
//    probe (R36) ALL neutral within fill-drift noise (+-10us).
//  - R36 null (double stores -> +0us) proves HBM bytes didn't double: 256MiB
//    output ~= 256MiB Infinity Cache; rewrites merge in MALL. No write-side
//    manipulation can matter — kernel is at the streaming-write roofline.
//  - Composite dur_us = harness 1GiB poison fill (~165-185, drifts) +
//    ~42us hidden 256MiB out-poison + kernel ~47-50us (vs 43us floor for
//    256MiB write + 8MiB read at 6.3TB/s achievable).
// Numerics: census-proven f32+FMA recurrence, f32 0.0/1.0 out, [B,T,F]:
//   acc += x; m = acc>=thr; sp = m?1:0; acc = m?0:acc;
//   thr = fmaf(thr, 0.9f, 0.1f*|x|)   <- single rounding (matches XLA fusion)

#define TSTEPS 32
#define BDIM 32
#define FDIM 65536

typedef float floatx4 __attribute__((ext_vector_type(4)));

__global__ __launch_bounds__(256) void spike_fma_f32_kernel(
    const float* __restrict__ x, float* __restrict__ out) {
    int gid = blockIdx.x * blockDim.x + threadIdx.x;   // 0 .. B*F/4-1
    int fi  = gid & (FDIM / 4 - 1);                    // 0..16383
    int b   = gid >> 14;                               // F/4 = 16384
    int f   = fi << 2;

    const floatx4 xv = *reinterpret_cast<const floatx4*>(x + (size_t)b * FDIM + f);
    float xs[4] = {xv.x, xv.y, xv.z, xv.w};

    float acc[4], thr[4], ad[4];
#pragma unroll
    for (int i = 0; i < 4; ++i) {
        acc[i] = 0.0f;
        thr[i] = 0.5f;
        ad[i]  = 0.1f * fabsf(xs[i]);   // one rounding
    }

    float* outb = out + (size_t)b * TSTEPS * FDIM + f;

#pragma unroll
    for (int t = 0; t < TSTEPS; ++t) {
        floatx4 sp;
#pragma unroll
        for (int e = 0; e < 4; ++e) {
            acc[e] = acc[e] + xs[e];
            bool m = acc[e] >= thr[e];
            sp[e]  = m ? 1.0f : 0.0f;
            acc[e] = m ? 0.0f : acc[e];
            thr[e] = __builtin_fmaf(thr[e], 0.9f, ad[e]);   // fused, 1 rounding
        }
        *reinterpret_cast<floatx4*>(outb + (size_t)t * FDIM) = sp;   // 16B store
    }
}

extern "C" void kernel_launch(void* const* d_in, const int* in_sizes, int n_in,
                              void* d_out, int out_size, void* d_ws, size_t ws_size,
                              hipStream_t stream) {
    (void)in_sizes; (void)n_in; (void)d_ws; (void)ws_size; (void)out_size;
    const float* x = (const float*)d_in[0];
    float* out     = (float*)d_out;
    const int total_threads = BDIM * FDIM / 4;   // 524288
    spike_fma_f32_kernel<<<total_threads / 256, 256, 0, stream>>>(x, out);
}